// Round 2
// baseline (4551.617 us; speedup 1.0000x reference)
//
#include <hip/hip_runtime.h>
#include <math.h>

// Fused ConvTranspose3d(32->64,k5,s2,p2) + sum(C_out) + bias + MaxPool(2) + MaxPool(3)
// x: (16,32,48,48,48) f32, weight: (32,64,5,5,5) f32, bias: (64,) f32
// out: (16,1,15,15,15) f32
//
// y[od] = sum x[id]*cw[kd], od = 2*id-2+kd; final out[j] = max over od in [6j,6j+5]^3 + cb.
// Window row r relates to x-row li and kernel tap k via: r = 2*li + k - 4.
// Data is staged in LDS as bf16 channels-last: xt[pixel][16ch packed in 8 u32],
// weights pre-packed by fold_kernel as cw[125 taps][32ch packed in 16 u32].

#define XS (48*48*48)

__device__ __forceinline__ unsigned rne16(float f) {
    unsigned u = __float_as_uint(f);
    return (u + 0x7FFFu + ((u >> 16) & 1u)) >> 16;  // bf16 bits (RNE) in low 16
}

// ---------------- Kernel 1: fold weights over C_out, pack bf16 channels-last ----------------
// ws layout: u32[2000] = [pix 0..124][slot 0..15], slot s holds channels (2s, 2s+1).
// ws[2000] (as float) = summed bias.
__global__ void fold_kernel(const float* __restrict__ w,
                            const float* __restrict__ bias,
                            unsigned* __restrict__ ws) {
    int t = blockIdx.x * blockDim.x + threadIdx.x;
    if (t < 2000) {
        int pix = t >> 4, sc = t & 15;
        const float* p0 = w + (size_t)(2 * sc) * 64 * 125 + pix;
        const float* p1 = p0 + 64 * 125;
        float s0 = 0.f, s1 = 0.f;
        #pragma unroll 8
        for (int o = 0; o < 64; ++o) { s0 += p0[o * 125]; s1 += p1[o * 125]; }
        ws[t] = rne16(s0) | (rne16(s1) << 16);
    } else if (t == 2000) {
        float s = 0.f;
        for (int o = 0; o < 64; ++o) s += bias[o];
        ((float*)ws)[2000] = s;
    }
}

// ---------------- Kernel 2: fused conv + maxpool ----------------
// Block = 128 thr = fo(5 final outputs along w) x rd(6 d-window rows) x cg(4 channel quads).
// Per (chunk of 16 ch, d-tap): thread loads 5-pixel bf16x4 rows, 900 FMAs into 6x6 acc.
__global__ __launch_bounds__(128, 4)
void fused_kernel(const float* __restrict__ x,
                  const unsigned* __restrict__ wsrc,
                  float* __restrict__ out) {
    __shared__ unsigned xt[425 * 8];   // [pixel(5*5*17)][8 u32 = 16ch bf16], 13.6 KB
    __shared__ unsigned cwS[2000];     // [125][16 u32 = 32ch bf16], 8 KB
    __shared__ float red[30];

    const int tid = threadIdx.x;
    int bid = blockIdx.x;
    const int bw = bid % 3;  bid /= 3;
    const int jh = bid % 15; bid /= 15;
    const int jd = bid % 15; const int n = bid / 15;
    const int d0 = 3 * jd - 1, h0 = 3 * jh - 1, w0 = 15 * bw - 1;

    // stage packed weights once (500 x b128)
    for (int e = tid; e < 500; e += 128)
        ((uint4*)cwS)[e] = ((const uint4*)wsrc)[e];

    const int fo = tid / 24;        // 0..4
    const int r  = tid % 24;
    const int rd = r >> 2;          // 0..5
    const int cg = r & 3;           // 0..3 -> channels 4cg..4cg+3 of chunk
    const bool active = tid < 120;

    const int ntd  = (rd & 1) ? 2 : 3;
    const int kd0  = rd & 1;
    const int lid0 = (rd + 4 - kd0) >> 1;

    float acc[36];
    #pragma unroll
    for (int i = 0; i < 36; ++i) acc[i] = 0.f;

    const int c2  = tid & 7;        // staging: u32 slot = channel pair (2c2, 2c2+1)
    const int p00 = tid >> 3;

    for (int chunk = 0; chunk < 2; ++chunk) {
        __syncthreads();
        // stage 16 channels as bf16 pairs: xt[p][c2]
        {
            const float* xc0 = x + ((size_t)n * 32 + chunk * 16 + 2 * c2) * XS;
            const float* xc1 = xc0 + XS;
            for (int p = p00; p < 425; p += 16) {
                int dz = p / 85;
                int rm = p - dz * 85;
                int dy = rm / 17;
                int dx = rm - dy * 17;
                int gd = d0 + dz, gh = h0 + dy, gw = w0 + dx;
                unsigned v = 0;
                if (((unsigned)gd < 48u) & ((unsigned)gh < 48u) & ((unsigned)gw < 48u)) {
                    int off = (gd * 48 + gh) * 48 + gw;
                    v = rne16(xc0[off]) | (rne16(xc1[off]) << 16);
                }
                xt[p * 8 + c2] = v;
            }
        }
        __syncthreads();

        if (active) {
            #pragma unroll
            for (int a = 0; a < 3; ++a) {
                if (a < ntd) {
                    const int lid = lid0 - a;
                    const int kd  = kd0 + 2 * a;
                    const unsigned* xb = &xt[(lid * 85 + 3 * fo) * 8 + cg * 2];
                    const unsigned* wb = &cwS[kd * 25 * 16 + chunk * 8 + cg * 2];
                    #pragma unroll
                    for (int lih = 0; lih < 5; ++lih) {
                        float ibf[5][4];
                        #pragma unroll
                        for (int j = 0; j < 5; ++j) {
                            uint2 q = *(const uint2*)&xb[(lih * 17 + j) * 8];
                            ibf[j][0] = __uint_as_float(q.x << 16);
                            ibf[j][1] = __uint_as_float(q.x & 0xFFFF0000u);
                            ibf[j][2] = __uint_as_float(q.y << 16);
                            ibf[j][3] = __uint_as_float(q.y & 0xFFFF0000u);
                        }
                        #pragma unroll
                        for (int kh = 0; kh < 5; ++kh) {
                            const int rh = 2 * lih + kh - 4;
                            if (rh >= 0 && rh < 6) {
                                float wbf[5][4];
                                #pragma unroll
                                for (int kw = 0; kw < 5; ++kw) {
                                    uint2 q = *(const uint2*)&wb[(kh * 5 + kw) * 16];
                                    wbf[kw][0] = __uint_as_float(q.x << 16);
                                    wbf[kw][1] = __uint_as_float(q.x & 0xFFFF0000u);
                                    wbf[kw][2] = __uint_as_float(q.y << 16);
                                    wbf[kw][3] = __uint_as_float(q.y & 0xFFFF0000u);
                                }
                                #pragma unroll
                                for (int liw = 0; liw < 5; ++liw) {
                                    #pragma unroll
                                    for (int kw = 0; kw < 5; ++kw) {
                                        const int rw = 2 * liw + kw - 4;
                                        if (rw >= 0 && rw < 6) {
                                            #pragma unroll
                                            for (int ch = 0; ch < 4; ++ch)
                                                acc[rh * 6 + rw] =
                                                    fmaf(ibf[liw][ch], wbf[kw][ch],
                                                         acc[rh * 6 + rw]);
                                        }
                                    }
                                }
                            }
                        }
                    }
                }
            }
        }
    }

    // sum over cg (4 adjacent lanes), then max over the 6x6 slab
    if (active) {
        #pragma unroll
        for (int i = 0; i < 36; ++i) {
            acc[i] += __shfl_xor(acc[i], 1);
            acc[i] += __shfl_xor(acc[i], 2);
        }
        if (cg == 0) {
            float m = -INFINITY;
            #pragma unroll
            for (int i = 0; i < 36; ++i) m = fmaxf(m, acc[i]);
            red[fo * 6 + rd] = m;
        }
    }
    __syncthreads();
    if (tid < 5) {
        float m = -INFINITY;
        #pragma unroll
        for (int k = 0; k < 6; ++k) m = fmaxf(m, red[tid * 6 + k]);
        float cb = ((const float*)wsrc)[2000];
        out[(((size_t)n * 15 + jd) * 15 + jh) * 15 + 5 * bw + tid] = m + cb;
    }
}

extern "C" void kernel_launch(void* const* d_in, const int* in_sizes, int n_in,
                              void* d_out, int out_size, void* d_ws, size_t ws_size,
                              hipStream_t stream) {
    const float* x = (const float*)d_in[0];
    const float* w = (const float*)d_in[1];
    const float* b = (const float*)d_in[2];
    float* out = (float*)d_out;
    unsigned* ws = (unsigned*)d_ws;

    fold_kernel<<<8, 256, 0, stream>>>(w, b, ws);

    // grid: 3 jw-groups x 15 jh x 15 jd x 16 n
    fused_kernel<<<3 * 15 * 15 * 16, 128, 0, stream>>>(x, ws, out);
}

// Round 3
// 819.809 us; speedup vs baseline: 5.5520x; 5.5520x over previous
//
#include <hip/hip_runtime.h>
#include <math.h>

// Fused ConvTranspose3d(32->64,k5,s2,p2) + sum(C_out) + bias + MaxPool(2) + MaxPool(3)
// x: (16,32,48,48,48) f32, weight: (32,64,5,5,5) f32, bias: (64,) f32
// out: (16,1,15,15,15) f32
//
// y[od] = sum x[id]*cw[kd], od = 2*id-2+kd; final out[j] = max over od in [6j,6j+5]^3 + cb.
// Window row r relates to x-row li and kernel tap k via: r = 2*li + k - 4.
// Data is staged in LDS as bf16 channels-last: xt[pixel][16ch packed in 8 u32],
// weights pre-packed by fold_kernel as cw[125 taps][32ch packed in 16 u32].
//
// ROUND 3 FIX: __launch_bounds__(128,4) had capped VGPR at 64 -> massive scratch
// spill (FETCH 7.5GB / WRITE 9.1GB of spill traffic, VALUBusy 7%). Drop the
// min-waves clamp; live set ~100 regs fits in the default budget without spill.

#define XS (48*48*48)

__device__ __forceinline__ unsigned rne16(float f) {
    unsigned u = __float_as_uint(f);
    return (u + 0x7FFFu + ((u >> 16) & 1u)) >> 16;  // bf16 bits (RNE) in low 16
}

// ---------------- Kernel 1: fold weights over C_out, pack bf16 channels-last ----------------
// ws layout: u32[2000] = [pix 0..124][slot 0..15], slot s holds channels (2s, 2s+1).
// ws[2000] (as float) = summed bias.
__global__ void fold_kernel(const float* __restrict__ w,
                            const float* __restrict__ bias,
                            unsigned* __restrict__ ws) {
    int t = blockIdx.x * blockDim.x + threadIdx.x;
    if (t < 2000) {
        int pix = t >> 4, sc = t & 15;
        const float* p0 = w + (size_t)(2 * sc) * 64 * 125 + pix;
        const float* p1 = p0 + 64 * 125;
        float s0 = 0.f, s1 = 0.f;
        #pragma unroll 8
        for (int o = 0; o < 64; ++o) { s0 += p0[o * 125]; s1 += p1[o * 125]; }
        ws[t] = rne16(s0) | (rne16(s1) << 16);
    } else if (t == 2000) {
        float s = 0.f;
        for (int o = 0; o < 64; ++o) s += bias[o];
        ((float*)ws)[2000] = s;
    }
}

// ---------------- Kernel 2: fused conv + maxpool ----------------
// Block = 128 thr = fo(5 final outputs along w) x rd(6 d-window rows) x cg(4 channel quads).
// Per (chunk of 16 ch, d-tap): thread loads 5-pixel bf16x4 rows, 900 FMAs into 6x6 acc.
__global__ __launch_bounds__(128)
void fused_kernel(const float* __restrict__ x,
                  const unsigned* __restrict__ wsrc,
                  float* __restrict__ out) {
    __shared__ unsigned xt[425 * 8];   // [pixel(5*5*17)][8 u32 = 16ch bf16], 13.6 KB
    __shared__ unsigned cwS[2000];     // [125][16 u32 = 32ch bf16], 8 KB
    __shared__ float red[30];

    const int tid = threadIdx.x;
    int bid = blockIdx.x;
    const int bw = bid % 3;  bid /= 3;
    const int jh = bid % 15; bid /= 15;
    const int jd = bid % 15; const int n = bid / 15;
    const int d0 = 3 * jd - 1, h0 = 3 * jh - 1, w0 = 15 * bw - 1;

    // stage packed weights once (500 x b128)
    for (int e = tid; e < 500; e += 128)
        ((uint4*)cwS)[e] = ((const uint4*)wsrc)[e];

    const int fo = tid / 24;        // 0..4
    const int r  = tid % 24;
    const int rd = r >> 2;          // 0..5
    const int cg = r & 3;           // 0..3 -> channels 4cg..4cg+3 of chunk
    const bool active = tid < 120;

    const int ntd  = (rd & 1) ? 2 : 3;
    const int kd0  = rd & 1;
    const int lid0 = (rd + 4 - kd0) >> 1;

    float acc[36];
    #pragma unroll
    for (int i = 0; i < 36; ++i) acc[i] = 0.f;

    const int c2  = tid & 7;        // staging: u32 slot = channel pair (2c2, 2c2+1)
    const int p00 = tid >> 3;

    for (int chunk = 0; chunk < 2; ++chunk) {
        __syncthreads();
        // stage 16 channels as bf16 pairs: xt[p][c2]
        {
            const float* xc0 = x + ((size_t)n * 32 + chunk * 16 + 2 * c2) * XS;
            const float* xc1 = xc0 + XS;
            for (int p = p00; p < 425; p += 16) {
                int dz = p / 85;
                int rm = p - dz * 85;
                int dy = rm / 17;
                int dx = rm - dy * 17;
                int gd = d0 + dz, gh = h0 + dy, gw = w0 + dx;
                unsigned v = 0;
                if (((unsigned)gd < 48u) & ((unsigned)gh < 48u) & ((unsigned)gw < 48u)) {
                    int off = (gd * 48 + gh) * 48 + gw;
                    v = rne16(xc0[off]) | (rne16(xc1[off]) << 16);
                }
                xt[p * 8 + c2] = v;
            }
        }
        __syncthreads();

        if (active) {
            #pragma unroll
            for (int a = 0; a < 3; ++a) {
                if (a < ntd) {
                    const int lid = lid0 - a;
                    const int kd  = kd0 + 2 * a;
                    const unsigned* xb = &xt[(lid * 85 + 3 * fo) * 8 + cg * 2];
                    const unsigned* wb = &cwS[kd * 25 * 16 + chunk * 8 + cg * 2];
                    #pragma unroll
                    for (int lih = 0; lih < 5; ++lih) {
                        float ibf[5][4];
                        #pragma unroll
                        for (int j = 0; j < 5; ++j) {
                            uint2 q = *(const uint2*)&xb[(lih * 17 + j) * 8];
                            ibf[j][0] = __uint_as_float(q.x << 16);
                            ibf[j][1] = __uint_as_float(q.x & 0xFFFF0000u);
                            ibf[j][2] = __uint_as_float(q.y << 16);
                            ibf[j][3] = __uint_as_float(q.y & 0xFFFF0000u);
                        }
                        #pragma unroll
                        for (int kh = 0; kh < 5; ++kh) {
                            const int rh = 2 * lih + kh - 4;
                            if (rh >= 0 && rh < 6) {
                                float wbf[5][4];
                                #pragma unroll
                                for (int kw = 0; kw < 5; ++kw) {
                                    uint2 q = *(const uint2*)&wb[(kh * 5 + kw) * 16];
                                    wbf[kw][0] = __uint_as_float(q.x << 16);
                                    wbf[kw][1] = __uint_as_float(q.x & 0xFFFF0000u);
                                    wbf[kw][2] = __uint_as_float(q.y << 16);
                                    wbf[kw][3] = __uint_as_float(q.y & 0xFFFF0000u);
                                }
                                #pragma unroll
                                for (int liw = 0; liw < 5; ++liw) {
                                    #pragma unroll
                                    for (int kw = 0; kw < 5; ++kw) {
                                        const int rw = 2 * liw + kw - 4;
                                        if (rw >= 0 && rw < 6) {
                                            #pragma unroll
                                            for (int ch = 0; ch < 4; ++ch)
                                                acc[rh * 6 + rw] =
                                                    fmaf(ibf[liw][ch], wbf[kw][ch],
                                                         acc[rh * 6 + rw]);
                                        }
                                    }
                                }
                            }
                        }
                    }
                }
            }
        }
    }

    // sum over cg (4 adjacent lanes), then max over the 6x6 slab
    if (active) {
        #pragma unroll
        for (int i = 0; i < 36; ++i) {
            acc[i] += __shfl_xor(acc[i], 1);
            acc[i] += __shfl_xor(acc[i], 2);
        }
        if (cg == 0) {
            float m = -INFINITY;
            #pragma unroll
            for (int i = 0; i < 36; ++i) m = fmaxf(m, acc[i]);
            red[fo * 6 + rd] = m;
        }
    }
    __syncthreads();
    if (tid < 5) {
        float m = -INFINITY;
        #pragma unroll
        for (int k = 0; k < 6; ++k) m = fmaxf(m, red[tid * 6 + k]);
        float cb = ((const float*)wsrc)[2000];
        out[(((size_t)n * 15 + jd) * 15 + jh) * 15 + 5 * bw + tid] = m + cb;
    }
}

extern "C" void kernel_launch(void* const* d_in, const int* in_sizes, int n_in,
                              void* d_out, int out_size, void* d_ws, size_t ws_size,
                              hipStream_t stream) {
    const float* x = (const float*)d_in[0];
    const float* w = (const float*)d_in[1];
    const float* b = (const float*)d_in[2];
    float* out = (float*)d_out;
    unsigned* ws = (unsigned*)d_ws;

    fold_kernel<<<8, 256, 0, stream>>>(w, b, ws);

    // grid: 3 jw-groups x 15 jh x 15 jd x 16 n
    fused_kernel<<<3 * 15 * 15 * 16, 128, 0, stream>>>(x, ws, out);
}

// Round 5
// 296.135 us; speedup vs baseline: 15.3701x; 2.7684x over previous
//
#include <hip/hip_runtime.h>
#include <math.h>

// Fused ConvTranspose3d(32->64,k5,s2,p2) + sum(C_out) + bias + MaxPool(2) + MaxPool(3)
// x: (16,32,48,48,48) f32, weight: (32,64,5,5,5) f32, bias: (64,) f32
// out: (16,1,15,15,15) f32
//
// y[od] = sum x[id]*cw[kd], od = 2*id-2+kd; final out[j] = max over od in [6j,6j+5]^3 + cb.
// Window row r = 2*li + k - 4 (li = local input idx, k = kernel tap).
// Data staged in LDS as f16 channels-last: xt[pixel][16ch packed in 8 u32],
// weights pre-packed by fold_kernel as cw[125 taps][32ch packed in 16 u32].
// Inner product uses v_dot2_f32_f16 (__builtin_amdgcn_fdot2): packed f16 pairs
// straight from LDS, f32 accumulate, no unpack VALU.

#define XS (48*48*48)

typedef __fp16 h2 __attribute__((ext_vector_type(2)));  // matches builtin signatures
union UH { unsigned u; h2 h; };

__device__ __forceinline__ unsigned pk16(float a, float b) {
    UH r; r.h = __builtin_amdgcn_cvt_pkrtz(a, b);  // v_cvt_pkrtz_f16_f32
    return r.u;
}

// ---------------- Kernel 1: fold weights over C_out, pack f16 channels-last ----------------
// ws layout: u32[2000] = [pix 0..124][slot 0..15], slot s holds channels (2s, 2s+1).
// ws[2000] (as float) = summed bias.
__global__ void fold_kernel(const float* __restrict__ w,
                            const float* __restrict__ bias,
                            unsigned* __restrict__ ws) {
    int t = blockIdx.x * blockDim.x + threadIdx.x;
    if (t < 2000) {
        int pix = t >> 4, sc = t & 15;
        const float* p0 = w + (size_t)(2 * sc) * 64 * 125 + pix;
        const float* p1 = p0 + 64 * 125;
        float s0 = 0.f, s1 = 0.f;
        #pragma unroll 8
        for (int o = 0; o < 64; ++o) { s0 += p0[o * 125]; s1 += p1[o * 125]; }
        ws[t] = pk16(s0, s1);
    } else if (t == 2000) {
        float s = 0.f;
        for (int o = 0; o < 64; ++o) s += bias[o];
        ((float*)ws)[2000] = s;
    }
}

// ---------------- Kernel 2: fused conv + maxpool ----------------
// Block = 128 thr = fo(5 final outputs along w) x rd(6 d-window rows) x cg(4 channel quads).
// Per (16ch chunk, d-tap): cache 25 x-pixels (uint2 = 4ch f16) in regs, then per kh
// load one 5-tap weight row and run the valid (lih,liw,kw) taps as dot2 pairs.
__global__ __launch_bounds__(128)
void fused_kernel(const float* __restrict__ x,
                  const unsigned* __restrict__ wsrc,
                  float* __restrict__ out) {
    __shared__ unsigned xt[425 * 8];   // [pixel(5*5*17)][8 u32 = 16ch f16], 13.6 KB
    __shared__ unsigned cwS[2000];     // [125][16 u32 = 32ch f16], 8 KB
    __shared__ float red[30];

    const int tid = threadIdx.x;
    int bid = blockIdx.x;
    const int bw = bid % 3;  bid /= 3;
    const int jh = bid % 15; bid /= 15;
    const int jd = bid % 15; const int n = bid / 15;
    const int d0 = 3 * jd - 1, h0 = 3 * jh - 1, w0 = 15 * bw - 1;

    // stage packed weights once (500 x b128)
    for (int e = tid; e < 500; e += 128)
        ((uint4*)cwS)[e] = ((const uint4*)wsrc)[e];

    const int fo = tid / 24;        // 0..4
    const int r  = tid % 24;
    const int rd = r >> 2;          // 0..5
    const int cg = r & 3;           // 0..3 -> channels 4cg..4cg+3 of chunk
    const bool active = tid < 120;

    const int ntd  = (rd & 1) ? 2 : 3;
    const int kd0  = rd & 1;
    const int lid0 = (rd + 4 - kd0) >> 1;

    float acc[36];
    #pragma unroll
    for (int i = 0; i < 36; ++i) acc[i] = 0.f;

    const int c2  = tid & 7;        // staging: u32 slot = channel pair (2c2, 2c2+1)
    const int p00 = tid >> 3;

    for (int chunk = 0; chunk < 2; ++chunk) {
        __syncthreads();
        // stage 16 channels as f16 pairs: xt[p][c2]
        {
            const float* xc0 = x + ((size_t)n * 32 + chunk * 16 + 2 * c2) * XS;
            const float* xc1 = xc0 + XS;
            for (int p = p00; p < 425; p += 16) {
                int dz = p / 85;
                int rm = p - dz * 85;
                int dy = rm / 17;
                int dx = rm - dy * 17;
                int gd = d0 + dz, gh = h0 + dy, gw = w0 + dx;
                unsigned v = 0;
                if (((unsigned)gd < 48u) & ((unsigned)gh < 48u) & ((unsigned)gw < 48u)) {
                    int off = (gd * 48 + gh) * 48 + gw;
                    v = pk16(xc0[off], xc1[off]);
                }
                xt[p * 8 + c2] = v;
            }
        }
        __syncthreads();

        if (active) {
            #pragma unroll
            for (int a = 0; a < 3; ++a) {
                if (a < ntd) {
                    const int lid = lid0 - a;
                    const int kd  = kd0 + 2 * a;
                    const unsigned* xb = &xt[(lid * 85 + 3 * fo) * 8 + cg * 2];
                    const unsigned* wq = &cwS[kd * 25 * 16 + chunk * 8 + cg * 2];

                    // cache the full 5x5 pixel slab for this d-slice (4 ch = uint2 each)
                    uint2 ibr[5][5];
                    #pragma unroll
                    for (int ih = 0; ih < 5; ++ih)
                        #pragma unroll
                        for (int iw = 0; iw < 5; ++iw)
                            ibr[ih][iw] = *(const uint2*)&xb[(ih * 17 + iw) * 8];

                    #pragma unroll
                    for (int kh = 0; kh < 5; ++kh) {
                        uint2 wbr[5];
                        #pragma unroll
                        for (int kw = 0; kw < 5; ++kw)
                            wbr[kw] = *(const uint2*)&wq[(kh * 5 + kw) * 16];
                        #pragma unroll
                        for (int lih = 0; lih < 5; ++lih) {
                            const int rh = 2 * lih + kh - 4;
                            if (rh >= 0 && rh < 6) {
                                #pragma unroll
                                for (int liw = 0; liw < 5; ++liw) {
                                    #pragma unroll
                                    for (int kw = 0; kw < 5; ++kw) {
                                        const int rw = 2 * liw + kw - 4;
                                        if (rw >= 0 && rw < 6) {
                                            UH x0, x1, w0v, w1v;
                                            x0.u = ibr[lih][liw].x;
                                            x1.u = ibr[lih][liw].y;
                                            w0v.u = wbr[kw].x;
                                            w1v.u = wbr[kw].y;
                                            float s = acc[rh * 6 + rw];
                                            s = __builtin_amdgcn_fdot2(x0.h, w0v.h, s, false);
                                            s = __builtin_amdgcn_fdot2(x1.h, w1v.h, s, false);
                                            acc[rh * 6 + rw] = s;
                                        }
                                    }
                                }
                            }
                        }
                    }
                }
            }
        }
    }

    // sum over cg (4 adjacent lanes), then max over the 6x6 slab
    if (active) {
        #pragma unroll
        for (int i = 0; i < 36; ++i) {
            acc[i] += __shfl_xor(acc[i], 1);
            acc[i] += __shfl_xor(acc[i], 2);
        }
        if (cg == 0) {
            float m = -INFINITY;
            #pragma unroll
            for (int i = 0; i < 36; ++i) m = fmaxf(m, acc[i]);
            red[fo * 6 + rd] = m;
        }
    }
    __syncthreads();
    if (tid < 5) {
        float m = -INFINITY;
        #pragma unroll
        for (int k = 0; k < 6; ++k) m = fmaxf(m, red[tid * 6 + k]);
        float cb = ((const float*)wsrc)[2000];
        out[(((size_t)n * 15 + jd) * 15 + jh) * 15 + 5 * bw + tid] = m + cb;
    }
}

extern "C" void kernel_launch(void* const* d_in, const int* in_sizes, int n_in,
                              void* d_out, int out_size, void* d_ws, size_t ws_size,
                              hipStream_t stream) {
    const float* x = (const float*)d_in[0];
    const float* w = (const float*)d_in[1];
    const float* b = (const float*)d_in[2];
    float* out = (float*)d_out;
    unsigned* ws = (unsigned*)d_ws;

    fold_kernel<<<8, 256, 0, stream>>>(w, b, ws);

    // grid: 3 jw-groups x 15 jh x 15 jd x 16 n
    fused_kernel<<<3 * 15 * 15 * 16, 128, 0, stream>>>(x, ws, out);
}